// Round 3
// baseline (587.567 us; speedup 1.0000x reference)
//
#include <hip/hip_runtime.h>
#include <stdint.h>

typedef __attribute__((ext_vector_type(8))) short bf16x8;
typedef __attribute__((ext_vector_type(4))) float f32x4;

__device__ __forceinline__ unsigned short f2bf(float f) {
    union { float f; uint32_t u; } v; v.f = f;
    uint32_t r = (v.u + 0x7FFFu + ((v.u >> 16) & 1u)) >> 16;
    return (unsigned short)r;
}
__device__ __forceinline__ float bf2f(unsigned short u) {
    union { uint32_t u; float f; } v; v.u = ((uint32_t)u) << 16; return v.f;
}

#define WP_ELEMS  1081344      // 64 ktiles * 528 rows * 32 k
#define K2        15456        // head-GEMM K: 30*512 sampled + 96 coord slots (90 used)
#define W2P_ELEMS (144 * K2)   // 2,225,664
#define B_OFF     42240        // LDS offset of B staging (A is 528*80)

// ---- pack conv weights (+shape/cam rows 512..524) to bf16, K-tiled [kt][row][k] ----
__global__ void pack_convw_kernel(const float* __restrict__ cw,
                                  const float* __restrict__ sw,
                                  const float* __restrict__ camw,
                                  unsigned short* __restrict__ Wp) {
    int gid = blockIdx.x * 256 + threadIdx.x;
    if (gid >= WP_ELEMS) return;
    int kt  = gid / 16896;
    int rem = gid - kt * 16896;
    int row = rem >> 5;
    int c   = rem & 31;
    int k   = kt * 32 + c;
    float v = 0.f;
    if (row < 512)      v = cw[row * 2048 + k];
    else if (row < 522) v = sw[(row - 512) * 2048 + k];
    else if (row < 525) v = camw[(row - 522) * 2048 + k];
    Wp[gid] = f2bf(v);
}

// ---- pack root/pose weights to bf16 [o2][K2]; cols 15360.. are the coord columns ----
__global__ void pack_w2_kernel(const float* __restrict__ root_w,
                               const float* __restrict__ pose_w,
                               unsigned short* __restrict__ W2p) {
    int gid = blockIdx.x * 256 + threadIdx.x;
    if (gid >= W2P_ELEMS) return;
    int o2 = gid / K2;
    int kk = gid - o2 * K2;
    float v = 0.f;
    if (o2 < 132) {
        const float* wr = (o2 < 6) ? (root_w + o2 * 15450) : (pose_w + (o2 - 6) * 15450);
        if (kk < 15360) {
            int j = kk >> 9;
            int o = kk & 511;
            v = wr[j * 515 + o];
        } else {
            int c = kk - 15360;
            if (c < 90) {
                int j = c / 3, d = c - 3 * j;
                v = wr[j * 515 + 512 + d];
            }
        }
    }
    W2p[gid] = f2bf(v);
}

// ---- fold BN(eval)+conv bias into per-channel scale/bias ----
__global__ void bn_prep_kernel(const float* cb, const float* g, const float* be,
                               const float* m, const float* v, float* sbws) {
    int o = blockIdx.x * 256 + threadIdx.x;
    if (o >= 512) return;
    float s = g[o] * rsqrtf(v[o] + 1e-5f);
    sbws[2 * o]     = s;
    sbws[2 * o + 1] = be[o] + s * (cb[o] - m[o]);
}

// ---- main fused kernel: 2 batches/block conv GEMM (+pooled rows) + BN/ReLU + bilinear ----
__global__ __launch_bounds__(512, 2)
void conv_main_kernel(const float* __restrict__ img,
                      const float* __restrict__ jc,
                      const unsigned short* __restrict__ Wp,
                      const float* __restrict__ sbws,
                      const float* __restrict__ shape_b,
                      const float* __restrict__ cam_b,
                      unsigned short* __restrict__ sampled,
                      float* __restrict__ out) {
    __shared__ __align__(16) char smem[66048];   // staging 52480; epilogue f 65536; red 512
    const int t     = threadIdx.x;
    const int lane  = t & 63;
    const int w     = t >> 6;          // wave 0..7
    const int l15   = lane & 15;
    const int quad  = lane >> 4;
    const int bb    = t >> 8;          // staging batch (0/1)
    const int hw    = t & 63;
    const int kch   = (t >> 6) & 3;    // staging k-chunk (8 k each)
    const int wbb   = w & 1;           // wave's batch
    const int wmh   = w >> 1;          // wave's row-half: rows wmh*128..+127
    const int b0    = blockIdx.x * 2;

    f32x4 acc[8][4];
    f32x4 accX;
    #pragma unroll
    for (int mi = 0; mi < 8; ++mi)
        #pragma unroll
        for (int nt = 0; nt < 4; ++nt)
            acc[mi][nt] = (f32x4){0.f, 0.f, 0.f, 0.f};
    accX = (f32x4){0.f, 0.f, 0.f, 0.f};

    const float* gBbase = img + (size_t)(b0 + bb) * 131072 + (size_t)(kch * 8) * 64 + hw;

    int4 ta[4], ta4;
    float fb[8];
    {   // prefetch tile 0
        const int4* gA = (const int4*)Wp;
        #pragma unroll
        for (int i = 0; i < 4; ++i) ta[i] = gA[t + 512 * i];
        if (t < 64) ta4 = gA[t + 2048];
        #pragma unroll
        for (int j = 0; j < 8; ++j) fb[j] = gBbase[j * 64];
    }

    for (int kt = 0; kt < 64; ++kt) {
        __syncthreads();
        #pragma unroll
        for (int i = 0; i < 4; ++i) {
            int c2 = t + 512 * i;
            *(int4*)(smem + (c2 >> 2) * 80 + (c2 & 3) * 16) = ta[i];
        }
        if (t < 64) {
            int c2 = t + 2048;
            *(int4*)(smem + (c2 >> 2) * 80 + (c2 & 3) * 16) = ta4;
        }
        {
            int4 bv;
            bv.x = (int)((uint32_t)f2bf(fb[0]) | ((uint32_t)f2bf(fb[1]) << 16));
            bv.y = (int)((uint32_t)f2bf(fb[2]) | ((uint32_t)f2bf(fb[3]) << 16));
            bv.z = (int)((uint32_t)f2bf(fb[4]) | ((uint32_t)f2bf(fb[5]) << 16));
            bv.w = (int)((uint32_t)f2bf(fb[6]) | ((uint32_t)f2bf(fb[7]) << 16));
            *(int4*)(smem + B_OFF + bb * 5120 + hw * 80 + kch * 16) = bv;
        }
        __syncthreads();

        if (kt < 63) {   // register prefetch of tile kt+1, hidden under MFMA phase
            const int4* gA = (const int4*)(Wp + (size_t)(kt + 1) * 16896);
            #pragma unroll
            for (int i = 0; i < 4; ++i) ta[i] = gA[t + 512 * i];
            if (t < 64) ta4 = gA[t + 2048];
            const float* gB = gBbase + (size_t)((kt + 1) * 32) * 64;
            #pragma unroll
            for (int j = 0; j < 8; ++j) fb[j] = gB[j * 64];
        }

        const char* Bs = smem + B_OFF + wbb * 5120;
        bf16x8 bfr0 = *(const bf16x8*)(Bs + (0  + l15) * 80 + quad * 16);
        bf16x8 bfr1 = *(const bf16x8*)(Bs + (16 + l15) * 80 + quad * 16);
        bf16x8 bfr2 = *(const bf16x8*)(Bs + (32 + l15) * 80 + quad * 16);
        bf16x8 bfr3 = *(const bf16x8*)(Bs + (48 + l15) * 80 + quad * 16);
        #pragma unroll
        for (int mi = 0; mi < 8; ++mi) {
            bf16x8 afr = *(const bf16x8*)(smem + (wmh * 128 + mi * 16 + l15) * 80 + quad * 16);
            acc[mi][0] = __builtin_amdgcn_mfma_f32_16x16x32_bf16(afr, bfr0, acc[mi][0], 0, 0, 0);
            acc[mi][1] = __builtin_amdgcn_mfma_f32_16x16x32_bf16(afr, bfr1, acc[mi][1], 0, 0, 0);
            acc[mi][2] = __builtin_amdgcn_mfma_f32_16x16x32_bf16(afr, bfr2, acc[mi][2], 0, 0, 0);
            acc[mi][3] = __builtin_amdgcn_mfma_f32_16x16x32_bf16(afr, bfr3, acc[mi][3], 0, 0, 0);
        }
        {   // pooled rows 512..527: wave covers global col-frag wbb*4+wmh
            bf16x8 afrX = *(const bf16x8*)(smem + (512 + l15) * 80 + quad * 16);
            bf16x8 bfrX = *(const bf16x8*)(Bs + (wmh * 16 + l15) * 80 + quad * 16);
            accX = __builtin_amdgcn_mfma_f32_16x16x32_bf16(afrX, bfrX, accX, 0, 0, 0);
        }
    }

    __syncthreads();   // staging LDS dead; smem[0..65536) becomes f, red at 65536
    float* red = (float*)(smem + 65536);
    #pragma unroll
    for (int r = 0; r < 4; ++r) {
        float v = accX[r];
        v += __shfl_xor(v, 1);
        v += __shfl_xor(v, 2);
        v += __shfl_xor(v, 4);
        v += __shfl_xor(v, 8);
        if (l15 == 0) red[w * 16 + quad * 4 + r] = v;
    }

    const float2* sb2 = (const float2*)sbws;
    #pragma unroll
    for (int p = 0; p < 2; ++p) {
        if (p) __syncthreads();     // protect f overwrite between phases
        if (wbb == p) {             // waves of batch p write f (512 rows x 64 pos, XOR swizzle)
            #pragma unroll
            for (int mi = 0; mi < 8; ++mi) {
                #pragma unroll
                for (int r = 0; r < 4; ++r) {
                    int row = wmh * 128 + mi * 16 + quad * 4 + r;
                    float2 sb = sb2[row];
                    #pragma unroll
                    for (int nt = 0; nt < 4; ++nt) {
                        int col = nt * 16 + l15;
                        float v = fmaxf(acc[mi][nt][r] * sb.x + sb.y, 0.f);
                        *(unsigned short*)(smem + row * 128 + (((col + row) & 63) << 1)) = f2bf(v);
                    }
                }
            }
        }
        __syncthreads();

        const int b = b0 + p;
        const float* jcb = jc + b * 90;
        if (t < 16) {   // shape/cam: combine the 4 waves of batch p
            float v = (red[(p    ) * 16 + t] + red[(p + 2) * 16 + t] +
                       red[(p + 4) * 16 + t] + red[(p + 6) * 16 + t]) * 0.015625f;
            if (t < 10)      out[67584 + b * 10 + t] = v + shape_b[t];
            else if (t < 13) out[72704 + b * 3 + (t - 10)] = v + cam_b[t - 10];
        }
        if (t < 96) {   // coord K-columns 15360..15455 (pad = 0)
            float v = (t < 90) ? jcb[t] : 0.f;
            sampled[(size_t)b * K2 + 15360 + t] = f2bf(v);
        }

        // bilinear sampling: thread t owns channel o = t
        unsigned short* outs = sampled + (size_t)b * K2;
        const int o = t;
        for (int s = 0; s < 30; ++s) {
            float x = jcb[s * 3 + 0];
            float y = jcb[s * 3 + 1];
            float x0f = floorf(x), y0f = floorf(y);
            int x0 = (int)x0f, y0 = (int)y0f;
            int x1 = x0 + 1, y1 = y0 + 1;
            float wx1 = x - x0f, wy1 = y - y0f;
            float wx0 = 1.f - wx1, wy0 = 1.f - wy1;
            float vx0 = (x0 >= 0 && x0 < 8) ? 1.f : 0.f;
            float vx1 = (x1 >= 0 && x1 < 8) ? 1.f : 0.f;
            float vy0 = (y0 >= 0 && y0 < 8) ? 1.f : 0.f;
            float vy1 = (y1 >= 0 && y1 < 8) ? 1.f : 0.f;
            int cx0 = min(max(x0, 0), 7), cx1 = min(max(x1, 0), 7);
            int cy0 = min(max(y0, 0), 7), cy1 = min(max(y1, 0), 7);
            int p00 = cy0 * 8 + cx0, p01 = cy0 * 8 + cx1;
            int p10 = cy1 * 8 + cx0, p11 = cy1 * 8 + cx1;
            float w00 = wy0 * wx0 * vy0 * vx0, w01 = wy0 * wx1 * vy0 * vx1;
            float w10 = wy1 * wx0 * vy1 * vx0, w11 = wy1 * wx1 * vy1 * vx1;
            float vA = w00 * bf2f(*(unsigned short*)(smem + o * 128 + (((p00 + o) & 63) << 1)))
                     + w01 * bf2f(*(unsigned short*)(smem + o * 128 + (((p01 + o) & 63) << 1)))
                     + w10 * bf2f(*(unsigned short*)(smem + o * 128 + (((p10 + o) & 63) << 1)))
                     + w11 * bf2f(*(unsigned short*)(smem + o * 128 + (((p11 + o) & 63) << 1)));
            outs[s * 512 + o] = f2bf(vA);
        }
    }
}

// ---- head GEMM: partials(31x8 blocks of 64x144) = feat(512xK2)bf16 @ W2p^T, K split by joint ----
__global__ __launch_bounds__(256, 4)
void gemm2_kernel(const unsigned short* __restrict__ sampled,
                  const unsigned short* __restrict__ W2p,
                  float* __restrict__ part) {
    __shared__ __align__(16) char smem[16640];   // A: 64*80=5120, B: 144*80=11520
    const int t    = threadIdx.x;
    const int lane = t & 63;
    const int w    = t >> 6;
    const int l15  = lane & 15;
    const int quad = lane >> 4;
    const int m0   = blockIdx.x * 64;
    const int j    = blockIdx.y;
    const int k0   = j * 512;              // j==30 -> 15360 (coord columns)
    const int ktn  = (j == 30) ? 3 : 16;

    f32x4 acc[9];
    #pragma unroll
    for (int nt = 0; nt < 9; ++nt) acc[nt] = (f32x4){0.f, 0.f, 0.f, 0.f};

    for (int kt = 0; kt < ktn; ++kt) {
        __syncthreads();
        {
            int r = t >> 2, ci = t & 3;
            int4 d = *(const int4*)(sampled + (size_t)(m0 + r) * K2 + k0 + kt * 32 + ci * 8);
            *(int4*)(smem + r * 80 + ci * 16) = d;
        }
        #pragma unroll
        for (int i = 0; i < 3; ++i) {
            int c2 = t + 256 * i;
            if (c2 < 576) {
                int r = c2 >> 2, ci = c2 & 3;
                int4 d = *(const int4*)(W2p + (size_t)r * K2 + k0 + kt * 32 + ci * 8);
                *(int4*)(smem + 5120 + r * 80 + ci * 16) = d;
            }
        }
        __syncthreads();
        bf16x8 a = *(const bf16x8*)(smem + (w * 16 + l15) * 80 + quad * 16);
        #pragma unroll
        for (int nt = 0; nt < 9; ++nt) {
            bf16x8 bfv = *(const bf16x8*)(smem + 5120 + (nt * 16 + l15) * 80 + quad * 16);
            acc[nt] = __builtin_amdgcn_mfma_f32_16x16x32_bf16(a, bfv, acc[nt], 0, 0, 0);
        }
    }
    float* pout = part + (size_t)(j * 8 + blockIdx.x) * 9216;   // 64*144
    #pragma unroll
    for (int nt = 0; nt < 9; ++nt) {
        #pragma unroll
        for (int r = 0; r < 4; ++r) {
            pout[(w * 16 + quad * 4 + r) * 144 + nt * 16 + l15] = acc[nt][r];
        }
    }
}

// ---- sum 31 K-partials + bias -> final root/pose outputs ----
__global__ void reduce_out_kernel(const float* __restrict__ part,
                                  const float* __restrict__ root_b,
                                  const float* __restrict__ pose_b,
                                  float* __restrict__ out) {
    int gid = blockIdx.x * 256 + threadIdx.x;    // exactly 67584
    int m  = gid / 132;
    int o2 = gid - m * 132;
    float s = (o2 < 6) ? root_b[o2] : pose_b[o2 - 6];
    const float* p = part + (size_t)(m >> 6) * 9216 + (m & 63) * 144 + o2;
    #pragma unroll
    for (int j = 0; j < 31; ++j) s += p[(size_t)j * 8 * 9216];
    if (o2 < 6) out[m * 6 + o2] = s;
    else        out[3072 + m * 126 + (o2 - 6)] = s;
}

extern "C" void kernel_launch(void* const* d_in, const int* in_sizes, int n_in,
                              void* d_out, int out_size, void* d_ws, size_t ws_size,
                              hipStream_t stream) {
    const float* img     = (const float*)d_in[0];
    const float* jc      = (const float*)d_in[1];
    const float* conv_w  = (const float*)d_in[2];
    const float* conv_b  = (const float*)d_in[3];
    const float* bn_g    = (const float*)d_in[4];
    const float* bn_be   = (const float*)d_in[5];
    const float* bn_m    = (const float*)d_in[6];
    const float* bn_v    = (const float*)d_in[7];
    const float* root_w  = (const float*)d_in[8];
    const float* root_b  = (const float*)d_in[9];
    const float* pose_w  = (const float*)d_in[10];
    const float* pose_b  = (const float*)d_in[11];
    const float* shape_w = (const float*)d_in[12];
    const float* shape_b = (const float*)d_in[13];
    const float* cam_w   = (const float*)d_in[14];
    const float* cam_b   = (const float*)d_in[15];
    float* out = (float*)d_out;
    char* ws = (char*)d_ws;

    unsigned short* Wp   = (unsigned short*)(ws);                    // 2,162,688 B
    unsigned short* W2p  = (unsigned short*)(ws + 2162688);          // 4,451,328 B
    unsigned short* samp = (unsigned short*)(ws + 6614016);          // 15,826,944 B
    float* part          = (float*)(ws + 22440960);                  // 9,142,272 B
    float* sbws          = (float*)(ws + 31583232);                  // 4,096 B

    pack_convw_kernel<<<4224, 256, 0, stream>>>(conv_w, shape_w, cam_w, Wp);
    pack_w2_kernel<<<8694, 256, 0, stream>>>(root_w, pose_w, W2p);
    bn_prep_kernel<<<2, 256, 0, stream>>>(conv_b, bn_g, bn_be, bn_m, bn_v, sbws);
    conv_main_kernel<<<256, 512, 0, stream>>>(img, jc, Wp, sbws, shape_b, cam_b,
                                              samp, out);
    gemm2_kernel<<<dim3(8, 31), 256, 0, stream>>>(samp, W2p, part);
    reduce_out_kernel<<<264, 256, 0, stream>>>(part, root_b, pose_b, out);
}

// Round 4
// 513.888 us; speedup vs baseline: 1.1434x; 1.1434x over previous
//
#include <hip/hip_runtime.h>
#include <stdint.h>

typedef __attribute__((ext_vector_type(8))) short bf16x8;
typedef __attribute__((ext_vector_type(4))) float f32x4;

__device__ __forceinline__ unsigned short f2bf(float f) {
    union { float f; uint32_t u; } v; v.f = f;
    uint32_t r = (v.u + 0x7FFFu + ((v.u >> 16) & 1u)) >> 16;
    return (unsigned short)r;
}
__device__ __forceinline__ float bf2f(unsigned short u) {
    union { uint32_t u; float f; } v; v.u = ((uint32_t)u) << 16; return v.f;
}

#define WP_ELEMS  1081344      // 64 ktiles * 528 rows * 32 k
#define K2        15456        // head-GEMM K: 30*512 sampled + 96 coord slots (90 used)
#define W2P_ELEMS (144 * K2)   // 2,225,664

// ---- pack conv weights (+shape/cam rows 512..524) to bf16, K-tiled [kt][row][k] ----
__global__ void pack_convw_kernel(const float* __restrict__ cw,
                                  const float* __restrict__ sw,
                                  const float* __restrict__ camw,
                                  unsigned short* __restrict__ Wp) {
    int gid = blockIdx.x * 256 + threadIdx.x;
    if (gid >= WP_ELEMS) return;
    int kt  = gid / 16896;
    int rem = gid - kt * 16896;
    int row = rem >> 5;
    int c   = rem & 31;
    int k   = kt * 32 + c;
    float v = 0.f;
    if (row < 512)      v = cw[row * 2048 + k];
    else if (row < 522) v = sw[(row - 512) * 2048 + k];
    else if (row < 525) v = camw[(row - 522) * 2048 + k];
    Wp[gid] = f2bf(v);
}

// ---- pack root/pose weights to bf16 [o2][K2]; cols 15360.. are the coord columns ----
__global__ void pack_w2_kernel(const float* __restrict__ root_w,
                               const float* __restrict__ pose_w,
                               unsigned short* __restrict__ W2p) {
    int gid = blockIdx.x * 256 + threadIdx.x;
    if (gid >= W2P_ELEMS) return;
    int o2 = gid / K2;
    int kk = gid - o2 * K2;
    float v = 0.f;
    if (o2 < 132) {
        const float* wr = (o2 < 6) ? (root_w + o2 * 15450) : (pose_w + (o2 - 6) * 15450);
        if (kk < 15360) {
            int j = kk >> 9;
            int o = kk & 511;
            v = wr[j * 515 + o];
        } else {
            int c = kk - 15360;
            if (c < 90) {
                int j = c / 3, d = c - 3 * j;
                v = wr[j * 515 + 512 + d];
            }
        }
    }
    W2p[gid] = f2bf(v);
}

// ---- fold BN(eval)+conv bias into per-channel scale/bias ----
__global__ void bn_prep_kernel(const float* cb, const float* g, const float* be,
                               const float* m, const float* v, float* sbws) {
    int o = blockIdx.x * 256 + threadIdx.x;
    if (o >= 512) return;
    float s = g[o] * rsqrtf(v[o] + 1e-5f);
    sbws[2 * o]     = s;
    sbws[2 * o + 1] = be[o] + s * (cb[o] - m[o]);
}

// ---- main fused kernel: per (batch, ch-half) block; A-frags direct global->VGPR ----
// 256 thr, 33.3 KB LDS -> 4 blocks/CU. mb=1 block also handles pooled rows 512..527.
__global__ __launch_bounds__(256, 4)
void conv_main_kernel(const float* __restrict__ img,
                      const float* __restrict__ jc,
                      const unsigned short* __restrict__ Wp,
                      const float* __restrict__ sbws,
                      const float* __restrict__ shape_b,
                      const float* __restrict__ cam_b,
                      unsigned short* __restrict__ sampled,
                      float* __restrict__ out) {
    __shared__ __align__(16) char smem[33280];  // loop: B-stage [0,5120); epi: f [0,32768), red @32768
    const int t    = threadIdx.x;
    const int lane = t & 63;
    const int w    = t >> 6;          // 0..3
    const int l15  = lane & 15;
    const int quad = lane >> 4;
    const int b    = blockIdx.x >> 1; // batch-major: mb pair adjacent for L3 img reuse
    const int mb   = blockIdx.x & 1;
    const int R0   = mb << 8;         // channel-row base 0 / 256

    f32x4 acc[4][4];
    f32x4 accX = (f32x4){0.f, 0.f, 0.f, 0.f};
    #pragma unroll
    for (int mi = 0; mi < 4; ++mi)
        #pragma unroll
        for (int nt = 0; nt < 4; ++nt)
            acc[mi][nt] = (f32x4){0.f, 0.f, 0.f, 0.f};

    // B: thread stages hw=lane, k-chunk w (8 k), one b128 LDS write per iter
    const float* gB = img + (size_t)b * 131072 + w * 512 + lane;
    int4 bv;
    {
        float fb[8];
        #pragma unroll
        for (int j = 0; j < 8; ++j) fb[j] = gB[j * 64];
        bv.x = (int)((uint32_t)f2bf(fb[0]) | ((uint32_t)f2bf(fb[1]) << 16));
        bv.y = (int)((uint32_t)f2bf(fb[2]) | ((uint32_t)f2bf(fb[3]) << 16));
        bv.z = (int)((uint32_t)f2bf(fb[4]) | ((uint32_t)f2bf(fb[5]) << 16));
        bv.w = (int)((uint32_t)f2bf(fb[6]) | ((uint32_t)f2bf(fb[7]) << 16));
    }

    for (int kt = 0; kt < 64; ++kt) {
        __syncthreads();
        *(int4*)(smem + lane * 80 + w * 16) = bv;
        __syncthreads();

        if (kt < 63) {   // prefetch B tile kt+1; convert lands late in MFMA phase
            const float* g = gB + (size_t)(kt + 1) * 2048;
            float fb[8];
            #pragma unroll
            for (int j = 0; j < 8; ++j) fb[j] = g[j * 64];
            bv.x = (int)((uint32_t)f2bf(fb[0]) | ((uint32_t)f2bf(fb[1]) << 16));
            bv.y = (int)((uint32_t)f2bf(fb[2]) | ((uint32_t)f2bf(fb[3]) << 16));
            bv.z = (int)((uint32_t)f2bf(fb[4]) | ((uint32_t)f2bf(fb[5]) << 16));
            bv.w = (int)((uint32_t)f2bf(fb[6]) | ((uint32_t)f2bf(fb[7]) << 16));
        }

        // A-fragments: direct global->VGPR from pre-packed Wp (L2-resident, 1KB/wave-instr)
        const unsigned short* WpK = Wp + (size_t)kt * 16896;
        bf16x8 afr[4];
        #pragma unroll
        for (int mi = 0; mi < 4; ++mi)
            afr[mi] = *(const bf16x8*)(WpK + (R0 + w * 64 + mi * 16 + l15) * 32 + quad * 8);

        bf16x8 bfr0 = *(const bf16x8*)(smem + (0  + l15) * 80 + quad * 16);
        bf16x8 bfr1 = *(const bf16x8*)(smem + (16 + l15) * 80 + quad * 16);
        bf16x8 bfr2 = *(const bf16x8*)(smem + (32 + l15) * 80 + quad * 16);
        bf16x8 bfr3 = *(const bf16x8*)(smem + (48 + l15) * 80 + quad * 16);

        if (mb) {   // pooled rows 512..527; wave w covers col-frag w
            bf16x8 afrX = *(const bf16x8*)(WpK + (512 + l15) * 32 + quad * 8);
            bf16x8 bfrX = *(const bf16x8*)(smem + (w * 16 + l15) * 80 + quad * 16);
            accX = __builtin_amdgcn_mfma_f32_16x16x32_bf16(afrX, bfrX, accX, 0, 0, 0);
        }
        #pragma unroll
        for (int mi = 0; mi < 4; ++mi) {
            acc[mi][0] = __builtin_amdgcn_mfma_f32_16x16x32_bf16(afr[mi], bfr0, acc[mi][0], 0, 0, 0);
            acc[mi][1] = __builtin_amdgcn_mfma_f32_16x16x32_bf16(afr[mi], bfr1, acc[mi][1], 0, 0, 0);
            acc[mi][2] = __builtin_amdgcn_mfma_f32_16x16x32_bf16(afr[mi], bfr2, acc[mi][2], 0, 0, 0);
            acc[mi][3] = __builtin_amdgcn_mfma_f32_16x16x32_bf16(afr[mi], bfr3, acc[mi][3], 0, 0, 0);
        }
    }

    __syncthreads();   // B-stage dead; [0,32768) becomes f slab (256 rows x 64 pos, XOR swizzle)
    float* red = (float*)(smem + 32768);
    if (mb) {
        #pragma unroll
        for (int r = 0; r < 4; ++r) {
            float v = accX[r];
            v += __shfl_xor(v, 1);
            v += __shfl_xor(v, 2);
            v += __shfl_xor(v, 4);
            v += __shfl_xor(v, 8);
            if (l15 == 0) red[w * 16 + quad * 4 + r] = v;
        }
    }
    const float2* sb2 = (const float2*)sbws;
    #pragma unroll
    for (int mi = 0; mi < 4; ++mi) {
        #pragma unroll
        for (int r = 0; r < 4; ++r) {
            int lrow = w * 64 + mi * 16 + quad * 4 + r;
            float2 sb = sb2[R0 + lrow];
            #pragma unroll
            for (int nt = 0; nt < 4; ++nt) {
                int col = nt * 16 + l15;
                float v = fmaxf(acc[mi][nt][r] * sb.x + sb.y, 0.f);
                *(unsigned short*)(smem + lrow * 128 + (((col + lrow) & 63) << 1)) = f2bf(v);
            }
        }
    }
    __syncthreads();

    const float* jcb = jc + b * 90;
    if (mb) {
        if (t < 16) {   // shape/cam = bias + mean over 64 hw
            float v = (red[t] + red[16 + t] + red[32 + t] + red[48 + t]) * 0.015625f;
            if (t < 10)      out[67584 + b * 10 + t] = v + shape_b[t];
            else if (t < 13) out[72704 + b * 3 + (t - 10)] = v + cam_b[t - 10];
        }
    } else {
        if (t < 96) {   // coord K-columns 15360..15455 (pad = 0)
            float v = (t < 90) ? jcb[t] : 0.f;
            sampled[(size_t)b * K2 + 15360 + t] = f2bf(v);
        }
    }

    // bilinear sampling: thread t owns local channel t (global R0+t)
    unsigned short* outs = sampled + (size_t)b * K2 + R0;
    for (int s = 0; s < 30; ++s) {
        float x = jcb[s * 3 + 0];
        float y = jcb[s * 3 + 1];
        float x0f = floorf(x), y0f = floorf(y);
        int x0 = (int)x0f, y0 = (int)y0f;
        int x1 = x0 + 1, y1 = y0 + 1;
        float wx1 = x - x0f, wy1 = y - y0f;
        float wx0 = 1.f - wx1, wy0 = 1.f - wy1;
        float vx0 = (x0 >= 0 && x0 < 8) ? 1.f : 0.f;
        float vx1 = (x1 >= 0 && x1 < 8) ? 1.f : 0.f;
        float vy0 = (y0 >= 0 && y0 < 8) ? 1.f : 0.f;
        float vy1 = (y1 >= 0 && y1 < 8) ? 1.f : 0.f;
        int cx0 = min(max(x0, 0), 7), cx1 = min(max(x1, 0), 7);
        int cy0 = min(max(y0, 0), 7), cy1 = min(max(y1, 0), 7);
        int p00 = cy0 * 8 + cx0, p01 = cy0 * 8 + cx1;
        int p10 = cy1 * 8 + cx0, p11 = cy1 * 8 + cx1;
        float w00 = wy0 * wx0 * vy0 * vx0, w01 = wy0 * wx1 * vy0 * vx1;
        float w10 = wy1 * wx0 * vy1 * vx0, w11 = wy1 * wx1 * vy1 * vx1;
        float vA = w00 * bf2f(*(unsigned short*)(smem + t * 128 + (((p00 + t) & 63) << 1)))
                 + w01 * bf2f(*(unsigned short*)(smem + t * 128 + (((p01 + t) & 63) << 1)))
                 + w10 * bf2f(*(unsigned short*)(smem + t * 128 + (((p10 + t) & 63) << 1)))
                 + w11 * bf2f(*(unsigned short*)(smem + t * 128 + (((p11 + t) & 63) << 1)));
        outs[s * 512 + t] = f2bf(vA);
    }
}

// ---- head GEMM: partials(31x8 blocks of 64x144) = feat(512xK2)bf16 @ W2p^T, K split by joint ----
__global__ __launch_bounds__(256, 4)
void gemm2_kernel(const unsigned short* __restrict__ sampled,
                  const unsigned short* __restrict__ W2p,
                  float* __restrict__ part) {
    __shared__ __align__(16) char smem[16640];   // A: 64*80=5120, B: 144*80=11520
    const int t    = threadIdx.x;
    const int lane = t & 63;
    const int w    = t >> 6;
    const int l15  = lane & 15;
    const int quad = lane >> 4;
    const int m0   = blockIdx.x * 64;
    const int j    = blockIdx.y;
    const int k0   = j * 512;              // j==30 -> 15360 (coord columns)
    const int ktn  = (j == 30) ? 3 : 16;

    f32x4 acc[9];
    #pragma unroll
    for (int nt = 0; nt < 9; ++nt) acc[nt] = (f32x4){0.f, 0.f, 0.f, 0.f};

    for (int kt = 0; kt < ktn; ++kt) {
        __syncthreads();
        {
            int r = t >> 2, ci = t & 3;
            int4 d = *(const int4*)(sampled + (size_t)(m0 + r) * K2 + k0 + kt * 32 + ci * 8);
            *(int4*)(smem + r * 80 + ci * 16) = d;
        }
        #pragma unroll
        for (int i = 0; i < 3; ++i) {
            int c2 = t + 256 * i;
            if (c2 < 576) {
                int r = c2 >> 2, ci = c2 & 3;
                int4 d = *(const int4*)(W2p + (size_t)r * K2 + k0 + kt * 32 + ci * 8);
                *(int4*)(smem + 5120 + r * 80 + ci * 16) = d;
            }
        }
        __syncthreads();
        bf16x8 a = *(const bf16x8*)(smem + (w * 16 + l15) * 80 + quad * 16);
        #pragma unroll
        for (int nt = 0; nt < 9; ++nt) {
            bf16x8 bfv = *(const bf16x8*)(smem + 5120 + (nt * 16 + l15) * 80 + quad * 16);
            acc[nt] = __builtin_amdgcn_mfma_f32_16x16x32_bf16(a, bfv, acc[nt], 0, 0, 0);
        }
    }
    float* pout = part + (size_t)(j * 8 + blockIdx.x) * 9216;   // 64*144
    #pragma unroll
    for (int nt = 0; nt < 9; ++nt) {
        #pragma unroll
        for (int r = 0; r < 4; ++r) {
            pout[(w * 16 + quad * 4 + r) * 144 + nt * 16 + l15] = acc[nt][r];
        }
    }
}

// ---- sum 31 K-partials + bias -> final root/pose outputs ----
__global__ void reduce_out_kernel(const float* __restrict__ part,
                                  const float* __restrict__ root_b,
                                  const float* __restrict__ pose_b,
                                  float* __restrict__ out) {
    int gid = blockIdx.x * 256 + threadIdx.x;    // exactly 67584
    int m  = gid / 132;
    int o2 = gid - m * 132;
    float s = (o2 < 6) ? root_b[o2] : pose_b[o2 - 6];
    const float* p = part + (size_t)(m >> 6) * 9216 + (m & 63) * 144 + o2;
    #pragma unroll
    for (int j = 0; j < 31; ++j) s += p[(size_t)j * 8 * 9216];
    if (o2 < 6) out[m * 6 + o2] = s;
    else        out[3072 + m * 126 + (o2 - 6)] = s;
}

extern "C" void kernel_launch(void* const* d_in, const int* in_sizes, int n_in,
                              void* d_out, int out_size, void* d_ws, size_t ws_size,
                              hipStream_t stream) {
    const float* img     = (const float*)d_in[0];
    const float* jc      = (const float*)d_in[1];
    const float* conv_w  = (const float*)d_in[2];
    const float* conv_b  = (const float*)d_in[3];
    const float* bn_g    = (const float*)d_in[4];
    const float* bn_be   = (const float*)d_in[5];
    const float* bn_m    = (const float*)d_in[6];
    const float* bn_v    = (const float*)d_in[7];
    const float* root_w  = (const float*)d_in[8];
    const float* root_b  = (const float*)d_in[9];
    const float* pose_w  = (const float*)d_in[10];
    const float* pose_b  = (const float*)d_in[11];
    const float* shape_w = (const float*)d_in[12];
    const float* shape_b = (const float*)d_in[13];
    const float* cam_w   = (const float*)d_in[14];
    const float* cam_b   = (const float*)d_in[15];
    float* out = (float*)d_out;
    char* ws = (char*)d_ws;

    unsigned short* Wp   = (unsigned short*)(ws);                    // 2,162,688 B
    unsigned short* W2p  = (unsigned short*)(ws + 2162688);          // 4,451,328 B
    unsigned short* samp = (unsigned short*)(ws + 6614016);          // 15,826,944 B
    float* part          = (float*)(ws + 22440960);                  // 9,142,272 B
    float* sbws          = (float*)(ws + 31583232);                  // 4,096 B

    pack_convw_kernel<<<4224, 256, 0, stream>>>(conv_w, shape_w, cam_w, Wp);
    pack_w2_kernel<<<8694, 256, 0, stream>>>(root_w, pose_w, W2p);
    bn_prep_kernel<<<2, 256, 0, stream>>>(conv_b, bn_g, bn_be, bn_m, bn_v, sbws);
    conv_main_kernel<<<1024, 256, 0, stream>>>(img, jc, Wp, sbws, shape_b, cam_b,
                                               samp, out);
    gemm2_kernel<<<dim3(8, 31), 256, 0, stream>>>(samp, W2p, part);
    reduce_out_kernel<<<264, 256, 0, stream>>>(part, root_b, pose_b, out);
}